// Round 1
// baseline (623.884 us; speedup 1.0000x reference)
//
#include <hip/hip_runtime.h>

#define L 96
#define CH 7
#define K_FEAT 7328
#define Q_END 4752          // 96 + 4656
#define PRED 720
#define BATCH 256
#define M_TOT (BATCH*CH)    // 1792
#define BM 64
#define BN 64
#define BK 32
#define XSTRIDE 101

// Build feature index table: feat[b,k,c] = xv[t1]*xv[t2]*xv[t3] with xv[96]=1.0
__global__ void build_table(ushort4* __restrict__ tab) {
    int k = blockIdx.x * blockDim.x + threadIdx.x;
    if (k >= K_FEAT) return;
    unsigned short t1 = 96, t2 = 96, t3 = 0;
    if (k < L) {
        t3 = (unsigned short)k;                    // linear: x_k
    } else if (k < Q_END) {
        int r = k - L;                             // quadratic: x_i * x_{i+d}
        int i = 0, base = 0;
        while (base + (L - i) <= r) { base += L - i; ++i; }
        t2 = (unsigned short)i;
        t3 = (unsigned short)(i + (r - base));
    } else {
        int r = k - Q_END;                         // cubic: x_i * x_j * x_{j+d}
        int base = 0;
        for (int i = 0; i < CH; ++i) {
            for (int j = i; j < CH; ++j) {
                int len = L - j;
                if (r < base + len) {
                    t1 = (unsigned short)i;
                    t2 = (unsigned short)j;
                    t3 = (unsigned short)(j + (r - base));
                    tab[k] = make_ushort4(t1, t2, t3, 0);
                    return;
                }
                base += len;
            }
        }
    }
    tab[k] = make_ushort4(t1, t2, t3, 0);
}

__global__ __launch_bounds__(256) void fused_poly_gemm(
    const float* __restrict__ x,     // [256][96][7]
    const float* __restrict__ W,     // [720][7328]
    const float* __restrict__ bias,  // [720]
    const ushort4* __restrict__ tab, // [7328]
    float* __restrict__ out)         // [256][720][7]
{
    __shared__ float xt[BM][XSTRIDE];   // 64 rows of x (97 used, padded)
    __shared__ float At[BK][BM];
    __shared__ float Wt[BK][BN];

    const int tid = threadIdx.x;
    const int m0 = blockIdx.x * BM;
    const int n0 = blockIdx.y * BN;

    // Stage the 64 x-rows this block needs; xv[96] = 1.0 sentinel.
    for (int idx = tid; idx < BM * L; idx += 256) {
        int r = idx / L, t = idx - r * L;
        int m = m0 + r;
        int b = m / CH, c = m - b * CH;
        xt[r][t] = x[(b * L + t) * CH + c];
    }
    if (tid < BM) xt[tid][96] = 1.0f;
    __syncthreads();

    const int tm = tid & 15;    // m sub-tile (4 rows)
    const int tn = tid >> 4;    // n sub-tile (4 cols)

    float acc[4][4] = {};

    for (int k0 = 0; k0 < K_FEAT; k0 += BK) {
        // ---- stage W tile [BK][BN], coalesced float4 along k ----
        #pragma unroll
        for (int q = tid; q < 512; q += 256) {
            int n = q >> 3, kq = q & 7;
            float4 w;
            if (n0 + n < PRED) {
                w = *(const float4*)&W[(size_t)(n0 + n) * K_FEAT + k0 + kq * 4];
            } else {
                w = make_float4(0.f, 0.f, 0.f, 0.f);
            }
            Wt[kq * 4 + 0][n] = w.x;
            Wt[kq * 4 + 1][n] = w.y;
            Wt[kq * 4 + 2][n] = w.z;
            Wt[kq * 4 + 3][n] = w.w;
        }
        // ---- generate A tile [BK][BM] from x products ----
        {
            int k  = tid >> 3;     // 0..31
            int mg = tid & 7;      // 8 m's per thread
            ushort4 e = tab[k0 + k];
            float p[8];
            #pragma unroll
            for (int mm = 0; mm < 8; ++mm) {
                int m = mg * 8 + mm;
                p[mm] = xt[m][e.x] * xt[m][e.y] * xt[m][e.z];
            }
            *(float4*)&At[k][mg * 8]     = make_float4(p[0], p[1], p[2], p[3]);
            *(float4*)&At[k][mg * 8 + 4] = make_float4(p[4], p[5], p[6], p[7]);
        }
        __syncthreads();

        #pragma unroll 8
        for (int k = 0; k < BK; ++k) {
            float4 a = *(const float4*)&At[k][tm * 4];
            float4 w = *(const float4*)&Wt[k][tn * 4];
            acc[0][0] = fmaf(a.x, w.x, acc[0][0]);
            acc[0][1] = fmaf(a.x, w.y, acc[0][1]);
            acc[0][2] = fmaf(a.x, w.z, acc[0][2]);
            acc[0][3] = fmaf(a.x, w.w, acc[0][3]);
            acc[1][0] = fmaf(a.y, w.x, acc[1][0]);
            acc[1][1] = fmaf(a.y, w.y, acc[1][1]);
            acc[1][2] = fmaf(a.y, w.z, acc[1][2]);
            acc[1][3] = fmaf(a.y, w.w, acc[1][3]);
            acc[2][0] = fmaf(a.z, w.x, acc[2][0]);
            acc[2][1] = fmaf(a.z, w.y, acc[2][1]);
            acc[2][2] = fmaf(a.z, w.z, acc[2][2]);
            acc[2][3] = fmaf(a.z, w.w, acc[2][3]);
            acc[3][0] = fmaf(a.w, w.x, acc[3][0]);
            acc[3][1] = fmaf(a.w, w.y, acc[3][1]);
            acc[3][2] = fmaf(a.w, w.z, acc[3][2]);
            acc[3][3] = fmaf(a.w, w.w, acc[3][3]);
        }
        __syncthreads();
    }

    // ---- epilogue: scatter to out[b][p][c] + bias ----
    #pragma unroll
    for (int i = 0; i < 4; ++i) {
        int m = m0 + tm * 4 + i;
        int b = m / CH, c = m - b * CH;
        #pragma unroll
        for (int j = 0; j < 4; ++j) {
            int n = n0 + tn * 4 + j;
            if (n < PRED) {
                out[((size_t)b * PRED + n) * CH + c] = acc[i][j] + bias[n];
            }
        }
    }
}

extern "C" void kernel_launch(void* const* d_in, const int* in_sizes, int n_in,
                              void* d_out, int out_size, void* d_ws, size_t ws_size,
                              hipStream_t stream) {
    const float* x    = (const float*)d_in[0];
    const float* W    = (const float*)d_in[1];
    const float* bias = (const float*)d_in[2];
    float* out = (float*)d_out;
    ushort4* tab = (ushort4*)d_ws;   // 7328 * 8 B = 58.6 KB

    hipLaunchKernelGGL(build_table, dim3((K_FEAT + 255) / 256), dim3(256), 0, stream, tab);

    dim3 grid(M_TOT / BM, (PRED + BN - 1) / BN);
    hipLaunchKernelGGL(fused_poly_gemm, grid, dim3(256), 0, stream,
                       x, W, bias, tab, out);
}

// Round 2
// 261.250 us; speedup vs baseline: 2.3881x; 2.3881x over previous
//
#include <hip/hip_runtime.h>
#include <hip/hip_bf16.h>

#define L 96
#define CH 7
#define K_FEAT 7328
#define Q_END 4752          // 96 + 4656
#define PRED 720
#define BATCH 256
#define M_TOT (BATCH*CH)    // 1792
#define KT_TOT 229          // K_FEAT / 32
#define NSPLIT 8

typedef __attribute__((ext_vector_type(8))) short bf16x8;
typedef __attribute__((ext_vector_type(4))) float f32x4;

// ---------------- ws layout (bytes) ----------------
#define SZ_A    ((size_t)M_TOT * K_FEAT * 2)      // 26,263,552 (one bf16 matrix)
#define SZ_W    ((size_t)PRED * K_FEAT * 2)       // 10,552,320
#define OFF_AHI ((size_t)0)
#define OFF_ALO (OFF_AHI + SZ_A)
#define OFF_WHI (OFF_ALO + SZ_A)
#define OFF_WLO (OFF_WHI + SZ_W)
#define OFF_TAB (OFF_WLO + SZ_W)
#define WS_REQ  (OFF_TAB + (size_t)K_FEAT * 8)    // ~73.7 MB

static __device__ __forceinline__ unsigned short f2bf(float f) {
    __hip_bfloat16 h = __float2bfloat16(f);
    return *(unsigned short*)&h;
}
static __device__ __forceinline__ float bf2f(unsigned short u) {
    union { unsigned int i; float f; } x; x.i = ((unsigned int)u) << 16; return x.f;
}

// Build feature index table: feat[m,k] = xv[t1]*xv[t2]*xv[t3] with xv[96]=1.0
__global__ void build_table(ushort4* __restrict__ tab) {
    int k = blockIdx.x * blockDim.x + threadIdx.x;
    if (k >= K_FEAT) return;
    unsigned short t1 = 96, t2 = 96, t3 = 0;
    if (k < L) {
        t3 = (unsigned short)k;
    } else if (k < Q_END) {
        int r = k - L;
        int i = 0, base = 0;
        while (base + (L - i) <= r) { base += L - i; ++i; }
        t2 = (unsigned short)i;
        t3 = (unsigned short)(i + (r - base));
    } else {
        int r = k - Q_END;
        int base = 0;
        for (int i = 0; i < CH; ++i) {
            for (int j = i; j < CH; ++j) {
                int len = L - j;
                if (r < base + len) {
                    t1 = (unsigned short)i;
                    t2 = (unsigned short)j;
                    t3 = (unsigned short)(j + (r - base));
                    tab[k] = make_ushort4(t1, t2, t3, 0);
                    return;
                }
                base += len;
            }
        }
    }
    tab[k] = make_ushort4(t1, t2, t3, 0);
}

// Materialize split-bf16 feature matrix Ahi/Alo [M_TOT][K_FEAT]
__global__ __launch_bounds__(256) void featgen(
    const float* __restrict__ x, const ushort4* __restrict__ tab,
    unsigned short* __restrict__ Ahi, unsigned short* __restrict__ Alo) {
    const int K4 = K_FEAT / 4;  // 1832
    int gid = blockIdx.x * 256 + threadIdx.x;   // exact grid: M_TOT*K4
    int m = gid / K4, k4 = gid - m * K4;
    int k = k4 * 4;
    int b = m / CH, c = m - b * CH;
    const float* xb = x + (size_t)b * L * CH + c;
    ushort4 hi, lo;
    unsigned short* hp = &hi.x; unsigned short* lp = &lo.x;
    #pragma unroll
    for (int j = 0; j < 4; ++j) {
        ushort4 e = tab[k + j];
        float f1 = (e.x < L) ? xb[(int)e.x * CH] : 1.0f;
        float f2 = (e.y < L) ? xb[(int)e.y * CH] : 1.0f;
        float f3 = xb[(int)e.z * CH];
        float v = f1 * f2 * f3;
        unsigned short h = f2bf(v);
        hp[j] = h;
        lp[j] = f2bf(v - bf2f(h));
    }
    *(ushort4*)&Ahi[(size_t)m * K_FEAT + k] = hi;
    *(ushort4*)&Alo[(size_t)m * K_FEAT + k] = lo;
}

// Split W into hi/lo bf16 [PRED][K_FEAT]
__global__ __launch_bounds__(256) void wsplit(
    const float* __restrict__ W,
    unsigned short* __restrict__ Whi, unsigned short* __restrict__ Wlo) {
    const int K4 = K_FEAT / 4;
    int gid = blockIdx.x * 256 + threadIdx.x;
    if (gid >= PRED * K4) return;
    int n = gid / K4, k4 = gid - n * K4;
    int k = k4 * 4;
    ushort4 hi, lo;
    unsigned short* hp = &hi.x; unsigned short* lp = &lo.x;
    #pragma unroll
    for (int j = 0; j < 4; ++j) {
        float v = W[(size_t)n * K_FEAT + k + j];
        unsigned short h = f2bf(v);
        hp[j] = h;
        lp[j] = f2bf(v - bf2f(h));
    }
    *(ushort4*)&Whi[(size_t)n * K_FEAT + k] = hi;
    *(ushort4*)&Wlo[(size_t)n * K_FEAT + k] = lo;
}

// out[b][p][c] = bias[p]
__global__ __launch_bounds__(256) void init_out(
    float* __restrict__ out, const float* __restrict__ bias) {
    int gid = blockIdx.x * 256 + threadIdx.x;   // exact grid: BATCH*PRED*CH
    int p = (gid / CH) % PRED;
    out[gid] = bias[p];
}

// Split-bf16 MFMA GEMM: out[m][n] += sum_k feat[m][k] * W[n][k]
// 128x128 tile, 512 threads (8 waves as 2x4), wave tile 64x32, K-split via blockIdx.z
__global__ __launch_bounds__(512) void gemm_mfma(
    const unsigned short* __restrict__ Ahi_g, const unsigned short* __restrict__ Alo_g,
    const unsigned short* __restrict__ Whi_g, const unsigned short* __restrict__ Wlo_g,
    float* __restrict__ out) {
    __shared__ unsigned short Ahs[128][32];
    __shared__ unsigned short Als[128][32];
    __shared__ unsigned short Whs[128][32];
    __shared__ unsigned short Wls[128][32];

    const int tid = threadIdx.x;
    const int lane = tid & 63;
    const int wid = tid >> 6;          // 0..7
    const int wr = wid >> 2;           // 0..1  (m half, 64 rows)
    const int wc = wid & 3;            // 0..3  (n quarter, 32 cols)
    const int m0 = blockIdx.x * 128;
    const int n0 = blockIdx.y * 128;
    const int s = blockIdx.z;
    const int kt0 = (KT_TOT * s) / NSPLIT;
    const int kt1 = (KT_TOT * (s + 1)) / NSPLIT;

    const int srow = tid >> 2;         // 0..127
    const int sk8 = (tid & 3) * 8;     // 0,8,16,24 (ushort offset)
    const int lr = lane & 15;
    const int koff = (lane >> 4) * 8;

    f32x4 acc[4][2] = {};

    for (int kt = kt0; kt < kt1; ++kt) {
        const int kk = kt * 32;
        // ---- stage 4 tiles, 16B per thread per tile ----
        {
            const size_t aoff = (size_t)(m0 + srow) * K_FEAT + kk + sk8;
            *(uint4*)&Ahs[srow][sk8] = *(const uint4*)&Ahi_g[aoff];
            *(uint4*)&Als[srow][sk8] = *(const uint4*)&Alo_g[aoff];
            const int n = n0 + srow;
            if (n < PRED) {
                const size_t woff = (size_t)n * K_FEAT + kk + sk8;
                *(uint4*)&Whs[srow][sk8] = *(const uint4*)&Whi_g[woff];
                *(uint4*)&Wls[srow][sk8] = *(const uint4*)&Wlo_g[woff];
            } else {
                uint4 z = make_uint4(0, 0, 0, 0);
                *(uint4*)&Whs[srow][sk8] = z;
                *(uint4*)&Wls[srow][sk8] = z;
            }
        }
        __syncthreads();

        bf16x8 ah[4], al[4], wh[2], wl[2];
        #pragma unroll
        for (int mi = 0; mi < 4; ++mi) {
            ah[mi] = *(bf16x8*)&Ahs[wr * 64 + mi * 16 + lr][koff];
            al[mi] = *(bf16x8*)&Als[wr * 64 + mi * 16 + lr][koff];
        }
        #pragma unroll
        for (int ni = 0; ni < 2; ++ni) {
            wh[ni] = *(bf16x8*)&Whs[wc * 32 + ni * 16 + lr][koff];
            wl[ni] = *(bf16x8*)&Wls[wc * 32 + ni * 16 + lr][koff];
        }
        #pragma unroll
        for (int mi = 0; mi < 4; ++mi) {
            #pragma unroll
            for (int ni = 0; ni < 2; ++ni) {
                acc[mi][ni] = __builtin_amdgcn_mfma_f32_16x16x32_bf16(ah[mi], wh[ni], acc[mi][ni], 0, 0, 0);
                acc[mi][ni] = __builtin_amdgcn_mfma_f32_16x16x32_bf16(ah[mi], wl[ni], acc[mi][ni], 0, 0, 0);
                acc[mi][ni] = __builtin_amdgcn_mfma_f32_16x16x32_bf16(al[mi], wh[ni], acc[mi][ni], 0, 0, 0);
            }
        }
        __syncthreads();
    }

    // ---- epilogue: atomic accumulate (C/D: col=lane&15, row=(lane>>4)*4+reg) ----
    #pragma unroll
    for (int mi = 0; mi < 4; ++mi) {
        #pragma unroll
        for (int ni = 0; ni < 2; ++ni) {
            const int n = n0 + wc * 32 + ni * 16 + (lane & 15);
            if (n < PRED) {
                const int mrow = m0 + wr * 64 + mi * 16 + (lane >> 4) * 4;
                #pragma unroll
                for (int r = 0; r < 4; ++r) {
                    const int m = mrow + r;
                    const int b = m / CH, c = m - b * CH;
                    atomicAdd(&out[((size_t)b * PRED + n) * CH + c], acc[mi][ni][r]);
                }
            }
        }
    }
}

// ================= fallback (round-1 vector kernel, proven) =================
#define BM 64
#define BN 64
#define BK 32
#define XSTRIDE 101

__global__ __launch_bounds__(256) void fused_poly_gemm(
    const float* __restrict__ x, const float* __restrict__ W,
    const float* __restrict__ bias, const ushort4* __restrict__ tab,
    float* __restrict__ out) {
    __shared__ float xt[BM][XSTRIDE];
    __shared__ float At[BK][BM];
    __shared__ float Wt[BK][BN];

    const int tid = threadIdx.x;
    const int m0 = blockIdx.x * BM;
    const int n0 = blockIdx.y * BN;

    for (int idx = tid; idx < BM * L; idx += 256) {
        int r = idx / L, t = idx - r * L;
        int m = m0 + r;
        int b = m / CH, c = m - b * CH;
        xt[r][t] = x[(b * L + t) * CH + c];
    }
    if (tid < BM) xt[tid][96] = 1.0f;
    __syncthreads();

    const int tm = tid & 15;
    const int tn = tid >> 4;
    float acc[4][4] = {};

    for (int k0 = 0; k0 < K_FEAT; k0 += BK) {
        #pragma unroll
        for (int q = tid; q < 512; q += 256) {
            int n = q >> 3, kq = q & 7;
            float4 w;
            if (n0 + n < PRED) w = *(const float4*)&W[(size_t)(n0 + n) * K_FEAT + k0 + kq * 4];
            else w = make_float4(0.f, 0.f, 0.f, 0.f);
            Wt[kq * 4 + 0][n] = w.x; Wt[kq * 4 + 1][n] = w.y;
            Wt[kq * 4 + 2][n] = w.z; Wt[kq * 4 + 3][n] = w.w;
        }
        {
            int k = tid >> 3, mg = tid & 7;
            ushort4 e = tab[k0 + k];
            float p[8];
            #pragma unroll
            for (int mm = 0; mm < 8; ++mm) {
                int m = mg * 8 + mm;
                p[mm] = xt[m][e.x] * xt[m][e.y] * xt[m][e.z];
            }
            *(float4*)&At[k][mg * 8]     = make_float4(p[0], p[1], p[2], p[3]);
            *(float4*)&At[k][mg * 8 + 4] = make_float4(p[4], p[5], p[6], p[7]);
        }
        __syncthreads();
        #pragma unroll 8
        for (int k = 0; k < BK; ++k) {
            float4 a = *(const float4*)&At[k][tm * 4];
            float4 w = *(const float4*)&Wt[k][tn * 4];
            acc[0][0] = fmaf(a.x, w.x, acc[0][0]); acc[0][1] = fmaf(a.x, w.y, acc[0][1]);
            acc[0][2] = fmaf(a.x, w.z, acc[0][2]); acc[0][3] = fmaf(a.x, w.w, acc[0][3]);
            acc[1][0] = fmaf(a.y, w.x, acc[1][0]); acc[1][1] = fmaf(a.y, w.y, acc[1][1]);
            acc[1][2] = fmaf(a.y, w.z, acc[1][2]); acc[1][3] = fmaf(a.y, w.w, acc[1][3]);
            acc[2][0] = fmaf(a.z, w.x, acc[2][0]); acc[2][1] = fmaf(a.z, w.y, acc[2][1]);
            acc[2][2] = fmaf(a.z, w.z, acc[2][2]); acc[2][3] = fmaf(a.z, w.w, acc[2][3]);
            acc[3][0] = fmaf(a.w, w.x, acc[3][0]); acc[3][1] = fmaf(a.w, w.y, acc[3][1]);
            acc[3][2] = fmaf(a.w, w.z, acc[3][2]); acc[3][3] = fmaf(a.w, w.w, acc[3][3]);
        }
        __syncthreads();
    }
    #pragma unroll
    for (int i = 0; i < 4; ++i) {
        int m = m0 + tm * 4 + i;
        int b = m / CH, c = m - b * CH;
        #pragma unroll
        for (int j = 0; j < 4; ++j) {
            int n = n0 + tn * 4 + j;
            if (n < PRED) out[((size_t)b * PRED + n) * CH + c] = acc[i][j] + bias[n];
        }
    }
}

extern "C" void kernel_launch(void* const* d_in, const int* in_sizes, int n_in,
                              void* d_out, int out_size, void* d_ws, size_t ws_size,
                              hipStream_t stream) {
    const float* x    = (const float*)d_in[0];
    const float* W    = (const float*)d_in[1];
    const float* bias = (const float*)d_in[2];
    float* out = (float*)d_out;
    char* ws = (char*)d_ws;

    if (ws_size >= WS_REQ) {
        unsigned short* Ahi = (unsigned short*)(ws + OFF_AHI);
        unsigned short* Alo = (unsigned short*)(ws + OFF_ALO);
        unsigned short* Whi = (unsigned short*)(ws + OFF_WHI);
        unsigned short* Wlo = (unsigned short*)(ws + OFF_WLO);
        ushort4* tab = (ushort4*)(ws + OFF_TAB);

        hipLaunchKernelGGL(build_table, dim3((K_FEAT + 255) / 256), dim3(256), 0, stream, tab);
        hipLaunchKernelGGL(featgen, dim3(M_TOT * (K_FEAT / 4) / 256), dim3(256), 0, stream,
                           x, tab, Ahi, Alo);
        hipLaunchKernelGGL(wsplit, dim3((PRED * (K_FEAT / 4) + 255) / 256), dim3(256), 0, stream,
                           W, Whi, Wlo);
        hipLaunchKernelGGL(init_out, dim3(BATCH * PRED * CH / 256), dim3(256), 0, stream,
                           out, bias);
        hipLaunchKernelGGL(gemm_mfma, dim3(M_TOT / 128, (PRED + 127) / 128, NSPLIT), dim3(512),
                           0, stream, Ahi, Alo, Whi, Wlo, out);
    } else {
        ushort4* tab = (ushort4*)ws;
        hipLaunchKernelGGL(build_table, dim3((K_FEAT + 255) / 256), dim3(256), 0, stream, tab);
        dim3 grid(M_TOT / BM, (PRED + BN - 1) / BN);
        hipLaunchKernelGGL(fused_poly_gemm, grid, dim3(256), 0, stream, x, W, bias, tab, out);
    }
}

// Round 3
// 110.493 us; speedup vs baseline: 5.6464x; 2.3644x over previous
//
#include <hip/hip_runtime.h>
#include <hip/hip_bf16.h>

#define L 96
#define CH 7
#define K_FEAT 7328
#define K4 1832
#define Q_END 4752          // 96 + 4656
#define PRED 720
#define NPAD 768
#define BATCH 256
#define M_TOT (BATCH*CH)    // 1792
#define KT_TOT 229          // K_FEAT / 32
#define NSPLIT 6

typedef __attribute__((ext_vector_type(8))) short bf16x8;
typedef __attribute__((ext_vector_type(4))) float f32x4;

// ---------------- ws layout (bytes) ----------------
#define SZ_A    ((size_t)M_TOT * K_FEAT * 2)          // 26,263,552
#define SZ_W    ((size_t)NPAD * K_FEAT * 2)           // 11,255,808
#define SZ_PS   ((size_t)NSPLIT * M_TOT * NPAD * 4)   // 33,030,144
#define OFF_AH  ((size_t)0)
#define OFF_WH  (OFF_AH + SZ_A)
#define OFF_WL  (OFF_WH + SZ_W)
#define OFF_PS  (OFF_WL + SZ_W)
#define OFF_TAB (OFF_PS + SZ_PS)
#define WS_REQ  (OFF_TAB + (size_t)K_FEAT * 8)        // ~81.9 MB

static __device__ __forceinline__ unsigned short f2bf(float f) {
    __hip_bfloat16 h = __float2bfloat16(f);
    return *(unsigned short*)&h;
}
static __device__ __forceinline__ float bf2f(unsigned short u) {
    union { unsigned int i; float f; } x; x.i = ((unsigned int)u) << 16; return x.f;
}

// async 16B global -> LDS (dest = wave-uniform base + lane*16)
static __device__ __forceinline__ void async_cp16(const unsigned short* g, unsigned short* l) {
    __builtin_amdgcn_global_load_lds(
        (const __attribute__((address_space(1))) unsigned int*)g,
        (__attribute__((address_space(3))) unsigned int*)l, 16, 0, 0);
}

// Build feature index table: feat[m,k] = xv[t1]*xv[t2]*xv[t3] with xv[96]=1.0
__global__ void build_table(ushort4* __restrict__ tab) {
    int k = blockIdx.x * blockDim.x + threadIdx.x;
    if (k >= K_FEAT) return;
    unsigned short t1 = 96, t2 = 96, t3 = 0;
    if (k < L) {
        t3 = (unsigned short)k;
    } else if (k < Q_END) {
        int r = k - L;
        int i = 0, base = 0;
        while (base + (L - i) <= r) { base += L - i; ++i; }
        t2 = (unsigned short)i;
        t3 = (unsigned short)(i + (r - base));
    } else {
        int r = k - Q_END;
        int base = 0;
        for (int i = 0; i < CH; ++i) {
            for (int j = i; j < CH; ++j) {
                int len = L - j;
                if (r < base + len) {
                    t1 = (unsigned short)i;
                    t2 = (unsigned short)j;
                    t3 = (unsigned short)(j + (r - base));
                    tab[k] = make_ushort4(t1, t2, t3, 0);
                    return;
                }
                base += len;
            }
        }
    }
    tab[k] = make_ushort4(t1, t2, t3, 0);
}

// Materialize bf16 feature matrix Ah [M_TOT][K_FEAT]
__global__ __launch_bounds__(256) void featgen(
    const float* __restrict__ x, const ushort4* __restrict__ tab,
    unsigned short* __restrict__ Ah) {
    int gid = blockIdx.x * 256 + threadIdx.x;   // exact grid: M_TOT*K4
    int m = gid / K4, k4 = gid - m * K4;
    int k = k4 * 4;
    int b = m / CH, c = m - b * CH;
    const float* xb = x + (size_t)b * L * CH + c;
    ushort4 hi;
    unsigned short* hp = &hi.x;
    #pragma unroll
    for (int j = 0; j < 4; ++j) {
        ushort4 e = tab[k + j];
        float f1 = (e.x < L) ? xb[(int)e.x * CH] : 1.0f;
        float f2 = (e.y < L) ? xb[(int)e.y * CH] : 1.0f;
        float f3 = xb[(int)e.z * CH];
        hp[j] = f2bf(f1 * f2 * f3);
    }
    *(ushort4*)&Ah[(size_t)m * K_FEAT + k] = hi;
}

// Split W into hi/lo bf16, padded+zeroed to NPAD rows
__global__ __launch_bounds__(256) void wsplit(
    const float* __restrict__ W,
    unsigned short* __restrict__ Wh, unsigned short* __restrict__ Wl) {
    int gid = blockIdx.x * 256 + threadIdx.x;   // exact grid: NPAD*K4
    int n = gid / K4, k4 = gid - n * K4;
    int k = k4 * 4;
    ushort4 hi, lo;
    unsigned short* hp = &hi.x; unsigned short* lp = &lo.x;
    #pragma unroll
    for (int j = 0; j < 4; ++j) {
        float v = (n < PRED) ? W[(size_t)n * K_FEAT + k + j] : 0.0f;
        unsigned short h = f2bf(v);
        hp[j] = h;
        lp[j] = f2bf(v - bf2f(h));
    }
    *(ushort4*)&Wh[(size_t)n * K_FEAT + k] = hi;
    *(ushort4*)&Wl[(size_t)n * K_FEAT + k] = lo;
}

// 2-MFMA split GEMM: psum[s][m][n] = sum_k ah[m][k]*(wh+wl)[n][k]
// 128x128 tile, 256 threads (4 waves 2x2), wave tile 64x64, K-split via blockIdx.z
__global__ __launch_bounds__(256, 2) void gemm2(
    const unsigned short* __restrict__ Ah, const unsigned short* __restrict__ Wh,
    const unsigned short* __restrict__ Wl, float* __restrict__ ps) {
    __shared__ unsigned short Ahs[128 * 32];
    __shared__ unsigned short Whs[128 * 32];
    __shared__ unsigned short Wls[128 * 32];

    const int tid = threadIdx.x;
    const int lane = tid & 63;
    const int w = tid >> 6;            // 0..3
    const int wr = w >> 1, wc = w & 1; // wave 64x64 sub-tile
    const int m0 = blockIdx.x * 128;
    const int n0 = blockIdx.y * 128;
    const int s = blockIdx.z;
    const int kt0 = (KT_TOT * s) / NSPLIT;
    const int kt1 = (KT_TOT * (s + 1)) / NSPLIT;

    // ---- staging descriptors: each wave covers 2 KB of each 8 KB tile ----
    // linear LDS slot (row, chunk_lin); global chunk = chunk_lin ^ ((row>>1)&3)
    const int row0 = w * 32 + (lane >> 2);
    const int row1 = row0 + 16;
    const int c0 = (lane & 3) ^ ((row0 >> 1) & 3);
    const int c1 = (lane & 3) ^ ((row1 >> 1) & 3);
    const unsigned short* gA0 = Ah + (size_t)(m0 + row0) * K_FEAT + c0 * 8 + kt0 * 32;
    const unsigned short* gA1 = Ah + (size_t)(m0 + row1) * K_FEAT + c1 * 8 + kt0 * 32;
    const unsigned short* gH0 = Wh + (size_t)(n0 + row0) * K_FEAT + c0 * 8 + kt0 * 32;
    const unsigned short* gH1 = Wh + (size_t)(n0 + row1) * K_FEAT + c1 * 8 + kt0 * 32;
    const unsigned short* gL0 = Wl + (size_t)(n0 + row0) * K_FEAT + c0 * 8 + kt0 * 32;
    const unsigned short* gL1 = Wl + (size_t)(n0 + row1) * K_FEAT + c1 * 8 + kt0 * 32;
    unsigned short* lA0 = Ahs + (w * 2 + 0) * 512;   // 1024 B per wave-round
    unsigned short* lA1 = Ahs + (w * 2 + 1) * 512;
    unsigned short* lH0 = Whs + (w * 2 + 0) * 512;
    unsigned short* lH1 = Whs + (w * 2 + 1) * 512;
    unsigned short* lL0 = Wls + (w * 2 + 0) * 512;
    unsigned short* lL1 = Wls + (w * 2 + 1) * 512;

    // ---- fragment read byte-offsets (swizzled) ----
    const int lr = lane & 15;
    const int ck = lane >> 4;          // chunk 0..3 == k-offset/8
    int offA[4], offW[4];
    #pragma unroll
    for (int mi = 0; mi < 4; ++mi) {
        int r = wr * 64 + mi * 16 + lr;
        offA[mi] = r * 64 + ((ck ^ ((r >> 1) & 3)) << 4);
    }
    #pragma unroll
    for (int ni = 0; ni < 4; ++ni) {
        int r = wc * 64 + ni * 16 + lr;
        offW[ni] = r * 64 + ((ck ^ ((r >> 1) & 3)) << 4);
    }

    f32x4 acc[4][4] = {};

    for (int kt = kt0; kt < kt1; ++kt) {
        async_cp16(gA0, lA0); async_cp16(gA1, lA1);
        async_cp16(gH0, lH0); async_cp16(gH1, lH1);
        async_cp16(gL0, lL0); async_cp16(gL1, lL1);
        gA0 += 32; gA1 += 32; gH0 += 32; gH1 += 32; gL0 += 32; gL1 += 32;
        __syncthreads();   // drains vmcnt -> LDS tiles ready

        bf16x8 ah[4], wh[4], wl[4];
        #pragma unroll
        for (int mi = 0; mi < 4; ++mi)
            ah[mi] = *(const bf16x8*)((const char*)Ahs + offA[mi]);
        #pragma unroll
        for (int ni = 0; ni < 4; ++ni) {
            wh[ni] = *(const bf16x8*)((const char*)Whs + offW[ni]);
            wl[ni] = *(const bf16x8*)((const char*)Wls + offW[ni]);
        }
        #pragma unroll
        for (int mi = 0; mi < 4; ++mi) {
            #pragma unroll
            for (int ni = 0; ni < 4; ++ni) {
                acc[mi][ni] = __builtin_amdgcn_mfma_f32_16x16x32_bf16(ah[mi], wh[ni], acc[mi][ni], 0, 0, 0);
                acc[mi][ni] = __builtin_amdgcn_mfma_f32_16x16x32_bf16(ah[mi], wl[ni], acc[mi][ni], 0, 0, 0);
            }
        }
        __syncthreads();   // protect LDS before next iter's writes
    }

    // ---- epilogue: plain stores to psum slice ----
    float* pb = ps + (size_t)s * M_TOT * NPAD;
    #pragma unroll
    for (int mi = 0; mi < 4; ++mi) {
        #pragma unroll
        for (int ni = 0; ni < 4; ++ni) {
            const int n = n0 + wc * 64 + ni * 16 + lr;
            const int mr = m0 + wr * 64 + mi * 16 + ck * 4;
            #pragma unroll
            for (int r = 0; r < 4; ++r) {
                pb[(size_t)(mr + r) * NPAD + n] = acc[mi][ni][r];
            }
        }
    }
}

// out[b][p][c] = sum_s psum[s][m][n] + bias[p]
__global__ __launch_bounds__(256) void reduce_k(
    const float* __restrict__ ps, const float* __restrict__ bias,
    float* __restrict__ out) {
    int gid = blockIdx.x * 256 + threadIdx.x;   // exact grid: M_TOT*NPAD
    int m = gid / NPAD, n = gid - m * NPAD;
    if (n >= PRED) return;
    float acc = bias[n];
    #pragma unroll
    for (int s = 0; s < NSPLIT; ++s)
        acc += ps[(size_t)s * M_TOT * NPAD + gid];
    int b = m / CH, c = m - b * CH;
    out[((size_t)b * PRED + n) * CH + c] = acc;
}

// ================= fallback (round-1 vector kernel, proven) =================
#define BM 64
#define BN 64
#define BK 32
#define XSTRIDE 101

__global__ __launch_bounds__(256) void fused_poly_gemm(
    const float* __restrict__ x, const float* __restrict__ W,
    const float* __restrict__ bias, const ushort4* __restrict__ tab,
    float* __restrict__ out) {
    __shared__ float xt[BM][XSTRIDE];
    __shared__ float At[BK][BM];
    __shared__ float Wt[BK][BN];

    const int tid = threadIdx.x;
    const int m0 = blockIdx.x * BM;
    const int n0 = blockIdx.y * BN;

    for (int idx = tid; idx < BM * L; idx += 256) {
        int r = idx / L, t = idx - r * L;
        int m = m0 + r;
        int b = m / CH, c = m - b * CH;
        xt[r][t] = x[(b * L + t) * CH + c];
    }
    if (tid < BM) xt[tid][96] = 1.0f;
    __syncthreads();

    const int tm = tid & 15;
    const int tn = tid >> 4;
    float acc[4][4] = {};

    for (int k0 = 0; k0 < K_FEAT; k0 += BK) {
        #pragma unroll
        for (int q = tid; q < 512; q += 256) {
            int n = q >> 3, kq = q & 7;
            float4 w;
            if (n0 + n < PRED) w = *(const float4*)&W[(size_t)(n0 + n) * K_FEAT + k0 + kq * 4];
            else w = make_float4(0.f, 0.f, 0.f, 0.f);
            Wt[kq * 4 + 0][n] = w.x; Wt[kq * 4 + 1][n] = w.y;
            Wt[kq * 4 + 2][n] = w.z; Wt[kq * 4 + 3][n] = w.w;
        }
        {
            int k = tid >> 3, mg = tid & 7;
            ushort4 e = tab[k0 + k];
            float p[8];
            #pragma unroll
            for (int mm = 0; mm < 8; ++mm) {
                int m = mg * 8 + mm;
                p[mm] = xt[m][e.x] * xt[m][e.y] * xt[m][e.z];
            }
            *(float4*)&At[k][mg * 8]     = make_float4(p[0], p[1], p[2], p[3]);
            *(float4*)&At[k][mg * 8 + 4] = make_float4(p[4], p[5], p[6], p[7]);
        }
        __syncthreads();
        #pragma unroll 8
        for (int k = 0; k < BK; ++k) {
            float4 a = *(const float4*)&At[k][tm * 4];
            float4 w = *(const float4*)&Wt[k][tn * 4];
            acc[0][0] = fmaf(a.x, w.x, acc[0][0]); acc[0][1] = fmaf(a.x, w.y, acc[0][1]);
            acc[0][2] = fmaf(a.x, w.z, acc[0][2]); acc[0][3] = fmaf(a.x, w.w, acc[0][3]);
            acc[1][0] = fmaf(a.y, w.x, acc[1][0]); acc[1][1] = fmaf(a.y, w.y, acc[1][1]);
            acc[1][2] = fmaf(a.y, w.z, acc[1][2]); acc[1][3] = fmaf(a.y, w.w, acc[1][3]);
            acc[2][0] = fmaf(a.z, w.x, acc[2][0]); acc[2][1] = fmaf(a.z, w.y, acc[2][1]);
            acc[2][2] = fmaf(a.z, w.z, acc[2][2]); acc[2][3] = fmaf(a.z, w.w, acc[2][3]);
            acc[3][0] = fmaf(a.w, w.x, acc[3][0]); acc[3][1] = fmaf(a.w, w.y, acc[3][1]);
            acc[3][2] = fmaf(a.w, w.z, acc[3][2]); acc[3][3] = fmaf(a.w, w.w, acc[3][3]);
        }
        __syncthreads();
    }
    #pragma unroll
    for (int i = 0; i < 4; ++i) {
        int m = m0 + tm * 4 + i;
        int b = m / CH, c = m - b * CH;
        #pragma unroll
        for (int j = 0; j < 4; ++j) {
            int n = n0 + tn * 4 + j;
            if (n < PRED) out[((size_t)b * PRED + n) * CH + c] = acc[i][j] + bias[n];
        }
    }
}

extern "C" void kernel_launch(void* const* d_in, const int* in_sizes, int n_in,
                              void* d_out, int out_size, void* d_ws, size_t ws_size,
                              hipStream_t stream) {
    const float* x    = (const float*)d_in[0];
    const float* W    = (const float*)d_in[1];
    const float* bias = (const float*)d_in[2];
    float* out = (float*)d_out;
    char* ws = (char*)d_ws;

    if (ws_size >= WS_REQ) {
        unsigned short* Ah = (unsigned short*)(ws + OFF_AH);
        unsigned short* Wh = (unsigned short*)(ws + OFF_WH);
        unsigned short* Wl = (unsigned short*)(ws + OFF_WL);
        float* psum = (float*)(ws + OFF_PS);
        ushort4* tab = (ushort4*)(ws + OFF_TAB);

        hipLaunchKernelGGL(build_table, dim3((K_FEAT + 255) / 256), dim3(256), 0, stream, tab);
        hipLaunchKernelGGL(featgen, dim3(M_TOT * K4 / 256), dim3(256), 0, stream, x, tab, Ah);
        hipLaunchKernelGGL(wsplit, dim3(NPAD * K4 / 256), dim3(256), 0, stream, W, Wh, Wl);
        hipLaunchKernelGGL(gemm2, dim3(M_TOT / 128, NPAD / 128, NSPLIT), dim3(256), 0, stream,
                           Ah, Wh, Wl, psum);
        hipLaunchKernelGGL(reduce_k, dim3(M_TOT * NPAD / 256), dim3(256), 0, stream,
                           psum, bias, out);
    } else {
        ushort4* tab = (ushort4*)ws;
        hipLaunchKernelGGL(build_table, dim3((K_FEAT + 255) / 256), dim3(256), 0, stream, tab);
        dim3 grid(M_TOT / BM, (PRED + BN - 1) / BN);
        hipLaunchKernelGGL(fused_poly_gemm, grid, dim3(256), 0, stream, x, W, bias, tab, out);
    }
}

// Round 4
// 93.126 us; speedup vs baseline: 6.6993x; 1.1865x over previous
//
#include <hip/hip_runtime.h>
#include <hip/hip_bf16.h>

#define L 96
#define CH 7
#define K_FEAT 7328
#define K4 1832
#define Q_END 4752          // 96 + 4656
#define PRED 720
#define NPAD 768
#define BATCH 256
#define M_TOT (BATCH*CH)    // 1792
#define KT_TOT 229          // K_FEAT / 32
#define NSPLIT 6
#define WSPLIT_BLKS (NPAD * K4 / 256)   // 5496

typedef __attribute__((ext_vector_type(8))) short bf16x8;
typedef __attribute__((ext_vector_type(4))) float f32x4;

// ---------------- ws layout (bytes) ----------------
#define SZ_A    ((size_t)M_TOT * K_FEAT * 2)          // 26,263,552
#define SZ_W    ((size_t)NPAD * K_FEAT * 2)           // 11,255,808
#define SZ_PS   ((size_t)NSPLIT * M_TOT * NPAD * 4)   // 33,030,144
#define OFF_AH  ((size_t)0)
#define OFF_WH  (OFF_AH + SZ_A)
#define OFF_WL  (OFF_WH + SZ_W)
#define OFF_PS  (OFF_WL + SZ_W)
#define OFF_TAB (OFF_PS + SZ_PS)
#define WS_REQ  (OFF_TAB + (size_t)K_FEAT * 8)        // ~81.9 MB

static __device__ __forceinline__ unsigned short f2bf(float f) {
    __hip_bfloat16 h = __float2bfloat16(f);
    return *(unsigned short*)&h;
}
static __device__ __forceinline__ float bf2f(unsigned short u) {
    union { unsigned int i; float f; } x; x.i = ((unsigned int)u) << 16; return x.f;
}

// async 16B global -> LDS (dest = wave-uniform base + lane*16)
static __device__ __forceinline__ void async_cp16(const unsigned short* g, unsigned short* l) {
    __builtin_amdgcn_global_load_lds(
        (const __attribute__((address_space(1))) unsigned int*)g,
        (__attribute__((address_space(3))) unsigned int*)l, 16, 0, 0);
}

// feature k -> index triple (t1,t2,t3), xv[96]=1.0 sentinel
static __device__ ushort4 feat_idx(int k) {
    unsigned short t1 = 96, t2 = 96, t3 = 0;
    if (k < L) {
        t3 = (unsigned short)k;
    } else if (k < Q_END) {
        int r = k - L;
        int i = 0, base = 0;
        while (base + (L - i) <= r) { base += L - i; ++i; }
        t2 = (unsigned short)i;
        t3 = (unsigned short)(i + (r - base));
    } else {
        int r = k - Q_END;
        int base = 0;
        for (int i = 0; i < CH; ++i) {
            for (int j = i; j < CH; ++j) {
                int len = L - j;
                if (r < base + len) {
                    return make_ushort4((unsigned short)i, (unsigned short)j,
                                        (unsigned short)(j + (r - base)), 0);
                }
                base += len;
            }
        }
    }
    return make_ushort4(t1, t2, t3, 0);
}

__global__ void build_table(ushort4* __restrict__ tab) {
    int k = blockIdx.x * blockDim.x + threadIdx.x;
    if (k < K_FEAT) tab[k] = feat_idx(k);
}

// Fused: W hi/lo split (padded to NPAD rows) + index-table build
__global__ __launch_bounds__(256) void prep(
    const float* __restrict__ W,
    unsigned short* __restrict__ Wh, unsigned short* __restrict__ Wl,
    ushort4* __restrict__ tab) {
    int bid = blockIdx.x;
    int tid = threadIdx.x;
    if (bid < WSPLIT_BLKS) {
        int gid = bid * 256 + tid;
        int n = gid / K4, k4 = gid - n * K4;
        int k = k4 * 4;
        ushort4 hi, lo;
        unsigned short* hp = &hi.x; unsigned short* lp = &lo.x;
        #pragma unroll
        for (int j = 0; j < 4; ++j) {
            float v = (n < PRED) ? W[(size_t)n * K_FEAT + k + j] : 0.0f;
            unsigned short h = f2bf(v);
            hp[j] = h;
            lp[j] = f2bf(v - bf2f(h));
        }
        *(ushort4*)&Wh[(size_t)n * K_FEAT + k] = hi;
        *(ushort4*)&Wl[(size_t)n * K_FEAT + k] = lo;
    } else {
        int k = (bid - WSPLIT_BLKS) * 256 + tid;
        if (k < K_FEAT) tab[k] = feat_idx(k);
    }
}

// Materialize bf16 feature matrix Ah [M_TOT][K_FEAT]
__global__ __launch_bounds__(256) void featgen(
    const float* __restrict__ x, const ushort4* __restrict__ tab,
    unsigned short* __restrict__ Ah) {
    int gid = blockIdx.x * 256 + threadIdx.x;   // exact grid: M_TOT*K4
    int m = gid / K4, k4 = gid - m * K4;
    int k = k4 * 4;
    int b = m / CH, c = m - b * CH;
    const float* xb = x + (size_t)b * L * CH + c;
    ushort4 hi;
    unsigned short* hp = &hi.x;
    #pragma unroll
    for (int j = 0; j < 4; ++j) {
        ushort4 e = tab[k + j];
        float f1 = (e.x < L) ? xb[(int)e.x * CH] : 1.0f;
        float f2 = (e.y < L) ? xb[(int)e.y * CH] : 1.0f;
        float f3 = xb[(int)e.z * CH];
        hp[j] = f2bf(f1 * f2 * f3);
    }
    *(ushort4*)&Ah[(size_t)m * K_FEAT + k] = hi;
}

// 2-MFMA split GEMM, double-buffered 2-phase pipeline.
// 128x128 tile, 256 threads (4 waves 2x2), wave tile 64x64, K-split, XCD swizzle.
__global__ __launch_bounds__(256, 2) void gemm2(
    const unsigned short* __restrict__ Ah, const unsigned short* __restrict__ Wh,
    const unsigned short* __restrict__ Wl, float* __restrict__ ps) {
    __shared__ unsigned short S[2][3][128 * 32];   // [buf][A,Wh,Wl][tile]

    const int tid = threadIdx.x;
    const int lane = tid & 63;
    const int w = tid >> 6;            // 0..3
    const int wr = w >> 1, wc = w & 1; // wave 64x64 sub-tile

    // XCD-aware bijective swizzle: 504 blocks = 8 XCDs x 63
    const int id = blockIdx.x;
    const int nid = (id & 7) * 63 + (id >> 3);
    const int bx = nid % 14;
    const int rest = nid / 14;
    const int by = rest % 6;
    const int bz = rest / 6;
    const int m0 = bx * 128;
    const int n0 = by * 128;
    const int kt0 = (KT_TOT * bz) / NSPLIT;
    const int kt1 = (KT_TOT * (bz + 1)) / NSPLIT;

    // ---- staging descriptors: wave w covers rows [w*32, w*32+32) ----
    const int row0 = w * 32 + (lane >> 2);
    const int row1 = row0 + 16;
    const int c0 = (lane & 3) ^ ((row0 >> 1) & 3);   // source pre-swizzle (rule #21)
    const int c1 = (lane & 3) ^ ((row1 >> 1) & 3);
    const unsigned short* gA0 = Ah + (size_t)(m0 + row0) * K_FEAT + c0 * 8 + kt0 * 32;
    const unsigned short* gA1 = Ah + (size_t)(m0 + row1) * K_FEAT + c1 * 8 + kt0 * 32;
    const unsigned short* gH0 = Wh + (size_t)(n0 + row0) * K_FEAT + c0 * 8 + kt0 * 32;
    const unsigned short* gH1 = Wh + (size_t)(n0 + row1) * K_FEAT + c1 * 8 + kt0 * 32;
    const unsigned short* gL0 = Wl + (size_t)(n0 + row0) * K_FEAT + c0 * 8 + kt0 * 32;
    const unsigned short* gL1 = Wl + (size_t)(n0 + row1) * K_FEAT + c1 * 8 + kt0 * 32;
    const int wb0 = w * 1024;          // ushort offset of wave's first 1KB slab
    const int wb1 = w * 1024 + 512;

#define STAGE(B) do { \
        async_cp16(gA0, &S[B][0][wb0]); async_cp16(gA1, &S[B][0][wb1]); \
        async_cp16(gH0, &S[B][1][wb0]); async_cp16(gH1, &S[B][1][wb1]); \
        async_cp16(gL0, &S[B][2][wb0]); async_cp16(gL1, &S[B][2][wb1]); \
        gA0 += 32; gA1 += 32; gH0 += 32; gH1 += 32; gL0 += 32; gL1 += 32; \
    } while (0)

    // ---- fragment read byte-offsets (swizzled, same involution) ----
    const int lr = lane & 15;
    const int ck = lane >> 4;          // k-chunk 0..3
    int offA[4], offW[4];
    #pragma unroll
    for (int mi = 0; mi < 4; ++mi) {
        int r = wr * 64 + mi * 16 + lr;
        offA[mi] = r * 64 + ((ck ^ ((r >> 1) & 3)) << 4);
    }
    #pragma unroll
    for (int ni = 0; ni < 4; ++ni) {
        int r = wc * 64 + ni * 16 + lr;
        offW[ni] = r * 64 + ((ck ^ ((r >> 1) & 3)) << 4);
    }

    f32x4 acc[4][4] = {};

    // ---- 2-phase pipeline: prologue stage, then overlap next-stage with compute ----
    STAGE(0);
    __syncthreads();
    int cur = 0;
    for (int kt = kt0; kt < kt1; ++kt) {
        if (kt + 1 < kt1) STAGE(cur ^ 1);

        const char* baseA = (const char*)S[cur][0];
        const char* baseH = (const char*)S[cur][1];
        const char* baseL = (const char*)S[cur][2];
        bf16x8 ah[4], wh[4], wl[4];
        #pragma unroll
        for (int mi = 0; mi < 4; ++mi)
            ah[mi] = *(const bf16x8*)(baseA + offA[mi]);
        #pragma unroll
        for (int ni = 0; ni < 4; ++ni) {
            wh[ni] = *(const bf16x8*)(baseH + offW[ni]);
            wl[ni] = *(const bf16x8*)(baseL + offW[ni]);
        }
        #pragma unroll
        for (int mi = 0; mi < 4; ++mi) {
            #pragma unroll
            for (int ni = 0; ni < 4; ++ni) {
                acc[mi][ni] = __builtin_amdgcn_mfma_f32_16x16x32_bf16(ah[mi], wh[ni], acc[mi][ni], 0, 0, 0);
                acc[mi][ni] = __builtin_amdgcn_mfma_f32_16x16x32_bf16(ah[mi], wl[ni], acc[mi][ni], 0, 0, 0);
            }
        }
        __syncthreads();   // drains vmcnt(0): next tile landed; all waves done with cur
        cur ^= 1;
    }
#undef STAGE

    // ---- epilogue: plain stores to psum slice ----
    float* pb = ps + (size_t)bz * M_TOT * NPAD;
    #pragma unroll
    for (int mi = 0; mi < 4; ++mi) {
        #pragma unroll
        for (int ni = 0; ni < 4; ++ni) {
            const int n = n0 + wc * 64 + ni * 16 + lr;
            const int mr = m0 + wr * 64 + mi * 16 + ck * 4;
            #pragma unroll
            for (int r = 0; r < 4; ++r) {
                pb[(size_t)(mr + r) * NPAD + n] = acc[mi][ni][r];
            }
        }
    }
}

// out[b][p][c] = sum_s psum[s][b*CH+c][p] + bias[p]   (one thread per (b,p))
__global__ __launch_bounds__(256) void reduce_k(
    const float* __restrict__ ps, const float* __restrict__ bias,
    float* __restrict__ out) {
    int gid = blockIdx.x * 256 + threadIdx.x;   // exact grid: BATCH*PRED
    int b = gid / PRED, p = gid - b * PRED;
    float bv = bias[p];
    float o[CH];
    #pragma unroll
    for (int c = 0; c < CH; ++c) o[c] = bv;
    #pragma unroll
    for (int s = 0; s < NSPLIT; ++s) {
        const float* pb = ps + (size_t)s * M_TOT * NPAD + (size_t)b * CH * NPAD + p;
        #pragma unroll
        for (int c = 0; c < CH; ++c) o[c] += pb[(size_t)c * NPAD];
    }
    float* ob = out + (size_t)gid * CH;
    #pragma unroll
    for (int c = 0; c < CH; ++c) ob[c] = o[c];
}

// ================= fallback (round-1 vector kernel, proven) =================
#define BM 64
#define BN 64
#define BK 32
#define XSTRIDE 101

__global__ __launch_bounds__(256) void fused_poly_gemm(
    const float* __restrict__ x, const float* __restrict__ W,
    const float* __restrict__ bias, const ushort4* __restrict__ tab,
    float* __restrict__ out) {
    __shared__ float xt[BM][XSTRIDE];
    __shared__ float At[BK][BM];
    __shared__ float Wt[BK][BN];

    const int tid = threadIdx.x;
    const int m0 = blockIdx.x * BM;
    const int n0 = blockIdx.y * BN;

    for (int idx = tid; idx < BM * L; idx += 256) {
        int r = idx / L, t = idx - r * L;
        int m = m0 + r;
        int b = m / CH, c = m - b * CH;
        xt[r][t] = x[(b * L + t) * CH + c];
    }
    if (tid < BM) xt[tid][96] = 1.0f;
    __syncthreads();

    const int tm = tid & 15;
    const int tn = tid >> 4;
    float acc[4][4] = {};

    for (int k0 = 0; k0 < K_FEAT; k0 += BK) {
        #pragma unroll
        for (int q = tid; q < 512; q += 256) {
            int n = q >> 3, kq = q & 7;
            float4 wv;
            if (n0 + n < PRED) wv = *(const float4*)&W[(size_t)(n0 + n) * K_FEAT + k0 + kq * 4];
            else wv = make_float4(0.f, 0.f, 0.f, 0.f);
            Wt[kq * 4 + 0][n] = wv.x; Wt[kq * 4 + 1][n] = wv.y;
            Wt[kq * 4 + 2][n] = wv.z; Wt[kq * 4 + 3][n] = wv.w;
        }
        {
            int k = tid >> 3, mg = tid & 7;
            ushort4 e = tab[k0 + k];
            float p[8];
            #pragma unroll
            for (int mm = 0; mm < 8; ++mm) {
                int m = mg * 8 + mm;
                p[mm] = xt[m][e.x] * xt[m][e.y] * xt[m][e.z];
            }
            *(float4*)&At[k][mg * 8]     = make_float4(p[0], p[1], p[2], p[3]);
            *(float4*)&At[k][mg * 8 + 4] = make_float4(p[4], p[5], p[6], p[7]);
        }
        __syncthreads();
        #pragma unroll 8
        for (int k = 0; k < BK; ++k) {
            float4 a = *(const float4*)&At[k][tm * 4];
            float4 wv = *(const float4*)&Wt[k][tn * 4];
            acc[0][0] = fmaf(a.x, wv.x, acc[0][0]); acc[0][1] = fmaf(a.x, wv.y, acc[0][1]);
            acc[0][2] = fmaf(a.x, wv.z, acc[0][2]); acc[0][3] = fmaf(a.x, wv.w, acc[0][3]);
            acc[1][0] = fmaf(a.y, wv.x, acc[1][0]); acc[1][1] = fmaf(a.y, wv.y, acc[1][1]);
            acc[1][2] = fmaf(a.y, wv.z, acc[1][2]); acc[1][3] = fmaf(a.y, wv.w, acc[1][3]);
            acc[2][0] = fmaf(a.z, wv.x, acc[2][0]); acc[2][1] = fmaf(a.z, wv.y, acc[2][1]);
            acc[2][2] = fmaf(a.z, wv.z, acc[2][2]); acc[2][3] = fmaf(a.z, wv.w, acc[2][3]);
            acc[3][0] = fmaf(a.w, wv.x, acc[3][0]); acc[3][1] = fmaf(a.w, wv.y, acc[3][1]);
            acc[3][2] = fmaf(a.w, wv.z, acc[3][2]); acc[3][3] = fmaf(a.w, wv.w, acc[3][3]);
        }
        __syncthreads();
    }
    #pragma unroll
    for (int i = 0; i < 4; ++i) {
        int m = m0 + tm * 4 + i;
        int b = m / CH, c = m - b * CH;
        #pragma unroll
        for (int j = 0; j < 4; ++j) {
            int n = n0 + tn * 4 + j;
            if (n < PRED) out[((size_t)b * PRED + n) * CH + c] = acc[i][j] + bias[n];
        }
    }
}

extern "C" void kernel_launch(void* const* d_in, const int* in_sizes, int n_in,
                              void* d_out, int out_size, void* d_ws, size_t ws_size,
                              hipStream_t stream) {
    const float* x    = (const float*)d_in[0];
    const float* W    = (const float*)d_in[1];
    const float* bias = (const float*)d_in[2];
    float* out = (float*)d_out;
    char* ws = (char*)d_ws;

    if (ws_size >= WS_REQ) {
        unsigned short* Ah = (unsigned short*)(ws + OFF_AH);
        unsigned short* Wh = (unsigned short*)(ws + OFF_WH);
        unsigned short* Wl = (unsigned short*)(ws + OFF_WL);
        float* psum = (float*)(ws + OFF_PS);
        ushort4* tab = (ushort4*)(ws + OFF_TAB);

        hipLaunchKernelGGL(prep, dim3(WSPLIT_BLKS + (K_FEAT + 255) / 256), dim3(256), 0, stream,
                           W, Wh, Wl, tab);
        hipLaunchKernelGGL(featgen, dim3(M_TOT * K4 / 256), dim3(256), 0, stream, x, tab, Ah);
        hipLaunchKernelGGL(gemm2, dim3(14 * 6 * NSPLIT), dim3(256), 0, stream,
                           Ah, Wh, Wl, psum);
        hipLaunchKernelGGL(reduce_k, dim3(BATCH * PRED / 256), dim3(256), 0, stream,
                           psum, bias, out);
    } else {
        ushort4* tab = (ushort4*)ws;
        hipLaunchKernelGGL(build_table, dim3((K_FEAT + 255) / 256), dim3(256), 0, stream, tab);
        dim3 grid(M_TOT / BM, (PRED + BN - 1) / BN);
        hipLaunchKernelGGL(fused_poly_gemm, grid, dim3(256), 0, stream, x, W, bias, tab, out);
    }
}

// Round 5
// 83.297 us; speedup vs baseline: 7.4898x; 1.1180x over previous
//
#include <hip/hip_runtime.h>
#include <hip/hip_bf16.h>

#define L 96
#define CH 7
#define K_FEAT 7328
#define KPAD 7360           // 64 * 115 (zero-padded K)
#define K8 (KPAD / 8)       // 920 ushort8-chunks per row
#define KT64 115            // K-steps of 64
#define Q_END 4752          // 96 + 4656
#define PRED 720
#define NPAD 768
#define BATCH 256
#define M_TOT (BATCH * CH)  // 1792
#define NSPLIT 6
#define FEAT_BLKS BATCH             // 256 featgen blocks (1 per batch)
#define W_BLKS (NPAD * K8 / 256)    // 2760 W-split blocks

typedef __attribute__((ext_vector_type(8))) short bf16x8;
typedef __attribute__((ext_vector_type(4))) float f32x4;

// ---------------- ws layout (bytes) ----------------
#define SZ_A   ((size_t)M_TOT * KPAD * 2)           // 26,378,240
#define SZ_W   ((size_t)NPAD * KPAD * 2)            // 11,304,960
#define SZ_PS  ((size_t)NSPLIT * M_TOT * NPAD * 4)  // 33,030,144
#define OFF_AH ((size_t)0)
#define OFF_WH (OFF_AH + SZ_A)
#define OFF_PS (OFF_WH + SZ_W)
#define WS_REQ (OFF_PS + SZ_PS)                     // ~70.7 MB (<= 81.9 known-good)

static __device__ __forceinline__ unsigned short f2bf(float f) {
    __hip_bfloat16 h = __float2bfloat16(f);
    return *(unsigned short*)&h;
}

// async 16B global -> LDS (dest = wave-uniform base + lane*16)
static __device__ __forceinline__ void async_cp16(const unsigned short* g, unsigned short* l) {
    __builtin_amdgcn_global_load_lds(
        (const __attribute__((address_space(1))) unsigned int*)g,
        (__attribute__((address_space(3))) unsigned int*)l, 16, 0, 0);
}

// feature k -> index triple (t1,t2,t3), xv[96]=1.0 sentinel
static __device__ ushort4 feat_idx(int k) {
    unsigned short t1 = 96, t2 = 96, t3 = 0;
    if (k < L) {
        t3 = (unsigned short)k;
    } else if (k < Q_END) {
        int r = k - L;
        int i = 0, base = 0;
        while (base + (L - i) <= r) { base += L - i; ++i; }
        t2 = (unsigned short)i;
        t3 = (unsigned short)(i + (r - base));
    } else {
        int r = k - Q_END;
        int base = 0;
        for (int i = 0; i < CH; ++i) {
            for (int j = i; j < CH; ++j) {
                int len = L - j;
                if (r < base + len) {
                    return make_ushort4((unsigned short)i, (unsigned short)j,
                                        (unsigned short)(j + (r - base)), 0);
                }
                base += len;
            }
        }
    }
    return make_ushort4(t1, t2, t3, 0);
}

// advance (t1,t2,t3) by one feature index
static __device__ __forceinline__ void adv_idx(int& t1, int& t2, int& t3) {
    if (t1 == 96) {
        if (t2 == 96) {                       // linear
            if (t3 < L - 1) ++t3; else { t2 = 0; t3 = 0; }
        } else {                              // quadratic (i=t2, t3 in [i,95])
            if (t3 < L - 1) ++t3;
            else if (t2 < L - 1) { ++t2; t3 = t2; }
            else { t1 = 0; t2 = 0; t3 = 0; }  // -> cubic (0,0,0)
        }
    } else {                                  // cubic (i=t1, j=t2, t3 in [j,95])
        if (t3 < L - 1) ++t3;
        else if (t2 < CH - 1) { ++t2; t3 = t2; }
        else { ++t1; t2 = t1; t3 = t1; }
    }
}

// Fused prep: blocks [0,256) = featgen (one per batch, self-built LDS tab);
//             blocks [256, 256+W_BLKS) = W bf16 split (padded, zero-filled).
__global__ __launch_bounds__(256) void prep_all(
    const float* __restrict__ x, const float* __restrict__ W,
    unsigned short* __restrict__ Ah, unsigned short* __restrict__ Wh) {
    __shared__ ushort4 tab[K_FEAT];   // 58,624 B
    __shared__ float xl[CH][L + 1];   //  2,716 B

    const int bid = blockIdx.x;
    const int tid = threadIdx.x;

    if (bid < FEAT_BLKS) {
        const int b = bid;
        // stage x[b] (coalesced read), transpose to [c][t]; sentinel xl[c][96]=1
        for (int i = tid; i < L * CH; i += 256) {
            int t = i / CH, c = i - t * CH;
            xl[c][t] = x[(size_t)b * L * CH + i];
        }
        if (tid < CH) xl[tid][L] = 1.0f;
        // build tab: thread t owns k in [29t, 29t+29)
        {
            int k0 = tid * 29;
            if (k0 < K_FEAT) {
                ushort4 e0 = feat_idx(k0);
                int t1 = e0.x, t2 = e0.y, t3 = e0.z;
                int kend = k0 + 29; if (kend > K_FEAT) kend = K_FEAT;
                for (int k = k0; k < kend; ++k) {
                    tab[k] = make_ushort4((unsigned short)t1, (unsigned short)t2,
                                          (unsigned short)t3, 0);
                    adv_idx(t1, t2, t3);
                }
            }
        }
        __syncthreads();
        // compute features: ushort8 chunks, coalesced 16B stores
        for (int idx = tid; idx < CH * K8; idx += 256) {
            int c = idx / K8, ch8 = idx - c * K8;
            int k = ch8 * 8;
            unsigned short o[8];
            #pragma unroll
            for (int j = 0; j < 8; ++j) {
                int kk = k + j;
                float v = 0.0f;
                if (kk < K_FEAT) {
                    ushort4 e = tab[kk];
                    v = xl[c][e.x] * xl[c][e.y] * xl[c][e.z];
                }
                o[j] = f2bf(v);
            }
            *(uint4*)&Ah[(size_t)(b * CH + c) * KPAD + k] = *(uint4*)o;
        }
    } else {
        int gid = (bid - FEAT_BLKS) * 256 + tid;   // exact: NPAD*K8
        int n = gid / K8, ch8 = gid - n * K8;
        int k = ch8 * 8;
        unsigned short o[8];
        #pragma unroll
        for (int j = 0; j < 8; ++j) {
            int kk = k + j;
            float v = (n < PRED && kk < K_FEAT) ? W[(size_t)n * K_FEAT + kk] : 0.0f;
            o[j] = f2bf(v);
        }
        *(uint4*)&Wh[(size_t)n * KPAD + k] = *(uint4*)o;
    }
}

// Single-MFMA bf16 GEMM, BK=64, double-buffered 2-phase pipeline.
// 128x128 tile, 256 threads (4 waves 2x2), wave tile 64x64, K-split, XCD swizzle.
__global__ __launch_bounds__(256, 2) void gemm2(
    const unsigned short* __restrict__ Ah, const unsigned short* __restrict__ Wh,
    float* __restrict__ ps) {
    __shared__ unsigned short S[2][2][128 * 64];   // [buf][A,W][128 rows x 64 k] = 64 KB

    const int tid = threadIdx.x;
    const int lane = tid & 63;
    const int w = tid >> 6;            // 0..3
    const int wr = w >> 1, wc = w & 1; // wave 64x64 sub-tile

    // XCD-aware bijective swizzle: 504 blocks = 8 XCDs x 63
    const int id = blockIdx.x;
    const int nid = (id & 7) * 63 + (id >> 3);
    const int bx = nid % 14;
    const int rest = nid / 14;
    const int by = rest % 6;
    const int bz = rest / 6;
    const int m0 = bx * 128;
    const int n0 = by * 128;
    const int kt0 = (KT64 * bz) / NSPLIT;
    const int kt1 = (KT64 * (bz + 1)) / NSPLIT;

    // ---- staging: per wave 4 cp16 each for A and W; rows [w*32, w*32+32) ----
    // slot q*64+lane -> row = w*32 + q*8 + (lane>>3), chunk_lin = lane&7
    // source chunk = chunk_lin ^ (row&7); (row&7)==(lane>>3) so cg uniform in q
    const int cg = (lane & 7) ^ (lane >> 3);
    const unsigned short* gA[4];
    const unsigned short* gW[4];
    #pragma unroll
    for (int q = 0; q < 4; ++q) {
        int row = w * 32 + q * 8 + (lane >> 3);
        gA[q] = Ah + (size_t)(m0 + row) * KPAD + cg * 8 + kt0 * 64;
        gW[q] = Wh + (size_t)(n0 + row) * KPAD + cg * 8 + kt0 * 64;
    }

#define STAGE(B) do { \
        _Pragma("unroll") \
        for (int q = 0; q < 4; ++q) { \
            async_cp16(gA[q], &S[B][0][(w * 256 + q * 64) * 8]); \
            async_cp16(gW[q], &S[B][1][(w * 256 + q * 64) * 8]); \
            gA[q] += 64; gW[q] += 64; \
        } \
    } while (0)

    // ---- fragment read byte-offsets (same XOR involution) ----
    const int lr = lane & 15;
    const int ck = lane >> 4;          // k-quarter within half
    int offA[4][2], offW[4][2];
    #pragma unroll
    for (int mi = 0; mi < 4; ++mi) {
        int r = wr * 64 + mi * 16 + lr;
        #pragma unroll
        for (int h = 0; h < 2; ++h)
            offA[mi][h] = r * 128 + (((h * 4 + ck) ^ (r & 7)) << 4);
    }
    #pragma unroll
    for (int ni = 0; ni < 4; ++ni) {
        int r = wc * 64 + ni * 16 + lr;
        #pragma unroll
        for (int h = 0; h < 2; ++h)
            offW[ni][h] = r * 128 + (((h * 4 + ck) ^ (r & 7)) << 4);
    }

    f32x4 acc[4][4] = {};

    STAGE(0);
    __syncthreads();
    int cur = 0;
    for (int kt = kt0; kt < kt1; ++kt) {
        if (kt + 1 < kt1) STAGE(cur ^ 1);

        const char* baseA = (const char*)S[cur][0];
        const char* baseW = (const char*)S[cur][1];
        bf16x8 ah[4][2], wh[4][2];
        #pragma unroll
        for (int mi = 0; mi < 4; ++mi) {
            ah[mi][0] = *(const bf16x8*)(baseA + offA[mi][0]);
            ah[mi][1] = *(const bf16x8*)(baseA + offA[mi][1]);
        }
        #pragma unroll
        for (int ni = 0; ni < 4; ++ni) {
            wh[ni][0] = *(const bf16x8*)(baseW + offW[ni][0]);
            wh[ni][1] = *(const bf16x8*)(baseW + offW[ni][1]);
        }
        #pragma unroll
        for (int mi = 0; mi < 4; ++mi) {
            #pragma unroll
            for (int ni = 0; ni < 4; ++ni) {
                acc[mi][ni] = __builtin_amdgcn_mfma_f32_16x16x32_bf16(ah[mi][0], wh[ni][0], acc[mi][ni], 0, 0, 0);
                acc[mi][ni] = __builtin_amdgcn_mfma_f32_16x16x32_bf16(ah[mi][1], wh[ni][1], acc[mi][ni], 0, 0, 0);
            }
        }
        __syncthreads();   // drains vmcnt(0): next tile landed; cur free for reuse
        cur ^= 1;
    }
#undef STAGE

    // ---- epilogue: plain stores to psum slice ----
    float* pb = ps + (size_t)bz * M_TOT * NPAD;
    #pragma unroll
    for (int mi = 0; mi < 4; ++mi) {
        #pragma unroll
        for (int ni = 0; ni < 4; ++ni) {
            const int n = n0 + wc * 64 + ni * 16 + lr;
            const int mr = m0 + wr * 64 + mi * 16 + ck * 4;
            #pragma unroll
            for (int r = 0; r < 4; ++r) {
                pb[(size_t)(mr + r) * NPAD + n] = acc[mi][ni][r];
            }
        }
    }
}

// out[b][p][c] = sum_s psum[s][b*CH+c][p] + bias[p]   (one thread per (b,p))
__global__ __launch_bounds__(256) void reduce_k(
    const float* __restrict__ ps, const float* __restrict__ bias,
    float* __restrict__ out) {
    int gid = blockIdx.x * 256 + threadIdx.x;   // exact grid: BATCH*PRED
    int b = gid / PRED, p = gid - b * PRED;
    float bv = bias[p];
    float o[CH];
    #pragma unroll
    for (int c = 0; c < CH; ++c) o[c] = bv;
    #pragma unroll
    for (int s = 0; s < NSPLIT; ++s) {
        const float* pb = ps + (size_t)s * M_TOT * NPAD + (size_t)b * CH * NPAD + p;
        #pragma unroll
        for (int c = 0; c < CH; ++c) o[c] += pb[(size_t)c * NPAD];
    }
    float* ob = out + (size_t)gid * CH;
    #pragma unroll
    for (int c = 0; c < CH; ++c) ob[c] = o[c];
}

// ================= fallback (round-1 vector kernel, proven) =================
#define BM 64
#define BN 64
#define BK 32
#define XSTRIDE 101

__global__ void build_table(ushort4* __restrict__ tab) {
    int k = blockIdx.x * blockDim.x + threadIdx.x;
    if (k < K_FEAT) tab[k] = feat_idx(k);
}

__global__ __launch_bounds__(256) void fused_poly_gemm(
    const float* __restrict__ x, const float* __restrict__ W,
    const float* __restrict__ bias, const ushort4* __restrict__ tab,
    float* __restrict__ out) {
    __shared__ float xt[BM][XSTRIDE];
    __shared__ float At[BK][BM];
    __shared__ float Wt[BK][BN];

    const int tid = threadIdx.x;
    const int m0 = blockIdx.x * BM;
    const int n0 = blockIdx.y * BN;

    for (int idx = tid; idx < BM * L; idx += 256) {
        int r = idx / L, t = idx - r * L;
        int m = m0 + r;
        int b = m / CH, c = m - b * CH;
        xt[r][t] = x[(b * L + t) * CH + c];
    }
    if (tid < BM) xt[tid][96] = 1.0f;
    __syncthreads();

    const int tm = tid & 15;
    const int tn = tid >> 4;
    float acc[4][4] = {};

    for (int k0 = 0; k0 < K_FEAT; k0 += BK) {
        #pragma unroll
        for (int q = tid; q < 512; q += 256) {
            int n = q >> 3, kq = q & 7;
            float4 wv;
            if (n0 + n < PRED) wv = *(const float4*)&W[(size_t)(n0 + n) * K_FEAT + k0 + kq * 4];
            else wv = make_float4(0.f, 0.f, 0.f, 0.f);
            Wt[kq * 4 + 0][n] = wv.x; Wt[kq * 4 + 1][n] = wv.y;
            Wt[kq * 4 + 2][n] = wv.z; Wt[kq * 4 + 3][n] = wv.w;
        }
        {
            int k = tid >> 3, mg = tid & 7;
            ushort4 e = tab[k0 + k];
            float p[8];
            #pragma unroll
            for (int mm = 0; mm < 8; ++mm) {
                int m = mg * 8 + mm;
                p[mm] = xt[m][e.x] * xt[m][e.y] * xt[m][e.z];
            }
            *(float4*)&At[k][mg * 8]     = make_float4(p[0], p[1], p[2], p[3]);
            *(float4*)&At[k][mg * 8 + 4] = make_float4(p[4], p[5], p[6], p[7]);
        }
        __syncthreads();
        #pragma unroll 8
        for (int k = 0; k < BK; ++k) {
            float4 a = *(const float4*)&At[k][tm * 4];
            float4 wv = *(const float4*)&Wt[k][tn * 4];
            acc[0][0] = fmaf(a.x, wv.x, acc[0][0]); acc[0][1] = fmaf(a.x, wv.y, acc[0][1]);
            acc[0][2] = fmaf(a.x, wv.z, acc[0][2]); acc[0][3] = fmaf(a.x, wv.w, acc[0][3]);
            acc[1][0] = fmaf(a.y, wv.x, acc[1][0]); acc[1][1] = fmaf(a.y, wv.y, acc[1][1]);
            acc[1][2] = fmaf(a.y, wv.z, acc[1][2]); acc[1][3] = fmaf(a.y, wv.w, acc[1][3]);
            acc[2][0] = fmaf(a.z, wv.x, acc[2][0]); acc[2][1] = fmaf(a.z, wv.y, acc[2][1]);
            acc[2][2] = fmaf(a.z, wv.z, acc[2][2]); acc[2][3] = fmaf(a.z, wv.w, acc[2][3]);
            acc[3][0] = fmaf(a.w, wv.x, acc[3][0]); acc[3][1] = fmaf(a.w, wv.y, acc[3][1]);
            acc[3][2] = fmaf(a.w, wv.z, acc[3][2]); acc[3][3] = fmaf(a.w, wv.w, acc[3][3]);
        }
        __syncthreads();
    }
    #pragma unroll
    for (int i = 0; i < 4; ++i) {
        int m = m0 + tm * 4 + i;
        int b = m / CH, c = m - b * CH;
        #pragma unroll
        for (int j = 0; j < 4; ++j) {
            int n = n0 + tn * 4 + j;
            if (n < PRED) out[((size_t)b * PRED + n) * CH + c] = acc[i][j] + bias[n];
        }
    }
}

extern "C" void kernel_launch(void* const* d_in, const int* in_sizes, int n_in,
                              void* d_out, int out_size, void* d_ws, size_t ws_size,
                              hipStream_t stream) {
    const float* x    = (const float*)d_in[0];
    const float* W    = (const float*)d_in[1];
    const float* bias = (const float*)d_in[2];
    float* out = (float*)d_out;
    char* ws = (char*)d_ws;

    if (ws_size >= WS_REQ) {
        unsigned short* Ah = (unsigned short*)(ws + OFF_AH);
        unsigned short* Wh = (unsigned short*)(ws + OFF_WH);
        float* psum = (float*)(ws + OFF_PS);

        hipLaunchKernelGGL(prep_all, dim3(FEAT_BLKS + W_BLKS), dim3(256), 0, stream,
                           x, W, Ah, Wh);
        hipLaunchKernelGGL(gemm2, dim3(14 * 6 * NSPLIT), dim3(256), 0, stream,
                           Ah, Wh, psum);
        hipLaunchKernelGGL(reduce_k, dim3(BATCH * PRED / 256), dim3(256), 0, stream,
                           psum, bias, out);
    } else {
        ushort4* tab = (ushort4*)ws;
        hipLaunchKernelGGL(build_table, dim3((K_FEAT + 255) / 256), dim3(256), 0, stream, tab);
        dim3 grid(M_TOT / BM, (PRED + BN - 1) / BN);
        hipLaunchKernelGGL(fused_poly_gemm, grid, dim3(256), 0, stream, x, W, bias, tab, out);
    }
}

// Round 6
// 76.446 us; speedup vs baseline: 8.1611x; 1.0896x over previous
//
#include <hip/hip_runtime.h>
#include <hip/hip_bf16.h>

#define L 96
#define CH 7
#define K_FEAT 7328
#define KPAD 7360           // 64 * 115 (zero-padded K)
#define K8 (KPAD / 8)       // 920 ushort8-chunks per row
#define KT64 115            // K-steps of 64
#define Q_END 4752          // 96 + 4656
#define PRED 720
#define NPAD 768
#define BATCH 256
#define M_TOT (BATCH * CH)  // 1792
#define NSPLIT 6
#define W_BLKS (NPAD * K8 / 256)        // 2760
#define TAB_BLKS ((K_FEAT + 255) / 256) // 29

typedef __attribute__((ext_vector_type(8))) short bf16x8;
typedef __attribute__((ext_vector_type(4))) float f32x4;

// ---------------- ws layout (bytes) ----------------
#define SZ_A    ((size_t)M_TOT * KPAD * 2)           // 26,378,240
#define SZ_W    ((size_t)NPAD * KPAD * 2)            // 11,304,960
#define SZ_PS   ((size_t)NSPLIT * M_TOT * NPAD * 4)  // 33,030,144
#define OFF_AH  ((size_t)0)
#define OFF_WH  (OFF_AH + SZ_A)
#define OFF_PS  (OFF_WH + SZ_W)
#define OFF_TAB (OFF_PS + SZ_PS)
#define WS_REQ  (OFF_TAB + (size_t)K_FEAT * 8)       // ~70.8 MB

static __device__ __forceinline__ unsigned short f2bf(float f) {
    __hip_bfloat16 h = __float2bfloat16(f);
    return *(unsigned short*)&h;
}

// async 16B global -> LDS (dest = wave-uniform base + lane*16)
static __device__ __forceinline__ void async_cp16(const unsigned short* g, unsigned short* l) {
    __builtin_amdgcn_global_load_lds(
        (const __attribute__((address_space(1))) unsigned int*)g,
        (__attribute__((address_space(3))) unsigned int*)l, 16, 0, 0);
}

// feature k -> index triple (t1,t2,t3), xv[96]=1.0 sentinel
static __device__ ushort4 feat_idx(int k) {
    unsigned short t1 = 96, t2 = 96, t3 = 0;
    if (k < L) {
        t3 = (unsigned short)k;
    } else if (k < Q_END) {
        int r = k - L;
        int i = 0, base = 0;
        while (base + (L - i) <= r) { base += L - i; ++i; }
        t2 = (unsigned short)i;
        t3 = (unsigned short)(i + (r - base));
    } else {
        int r = k - Q_END;
        int base = 0;
        for (int i = 0; i < CH; ++i) {
            for (int j = i; j < CH; ++j) {
                int len = L - j;
                if (r < base + len) {
                    return make_ushort4((unsigned short)i, (unsigned short)j,
                                        (unsigned short)(j + (r - base)), 0);
                }
                base += len;
            }
        }
    }
    return make_ushort4(t1, t2, t3, 0);
}

// Streaming prep: blocks [0,W_BLKS) = W bf16 split (padded, zero-filled);
//                 blocks [W_BLKS, W_BLKS+TAB_BLKS) = index-table build. No LDS.
__global__ __launch_bounds__(256) void prep1(
    const float* __restrict__ W, unsigned short* __restrict__ Wh,
    ushort4* __restrict__ tab) {
    const int bid = blockIdx.x;
    const int tid = threadIdx.x;
    if (bid < W_BLKS) {
        int gid = bid * 256 + tid;                 // exact: NPAD*K8
        int n = gid / K8, ch8 = gid - n * K8;
        int k = ch8 * 8;
        unsigned short o[8];
        #pragma unroll
        for (int j = 0; j < 8; ++j) {
            int kk = k + j;
            float v = (n < PRED && kk < K_FEAT) ? W[(size_t)n * K_FEAT + kk] : 0.0f;
            o[j] = f2bf(v);
        }
        *(uint4*)&Wh[(size_t)n * KPAD + k] = *(uint4*)o;
    } else {
        int k = (bid - W_BLKS) * 256 + tid;
        if (k < K_FEAT) tab[k] = feat_idx(k);
    }
}

// Featgen: 4 blocks per batch; scalar elements so lane<->k is stride-1
// (conflict-free xl reads, coalesced 2B stores, coalesced 8B tab loads).
__global__ __launch_bounds__(256) void featgen3(
    const float* __restrict__ x, const ushort4* __restrict__ tab,
    unsigned short* __restrict__ Ah) {
    __shared__ float xl[CH][L + 1];   // 2,716 B
    const int b = blockIdx.x >> 2;
    const int part = blockIdx.x & 3;
    const int tid = threadIdx.x;

    for (int i = tid; i < L * CH; i += 256) {
        int t = i / CH, c = i - t * CH;
        xl[c][t] = x[(size_t)b * L * CH + i];
    }
    if (tid < CH) xl[tid][L] = 1.0f;
    __syncthreads();

    const int span = CH * KPAD / 4;   // 12880
    unsigned short* Ab = Ah + (size_t)b * CH * KPAD;
    const int e1 = (part + 1) * span;
    for (int e = part * span + tid; e < e1; e += 256) {
        int c = e / KPAD, kk = e - c * KPAD;
        float v = 0.0f;
        if (kk < K_FEAT) {
            ushort4 t = tab[kk];
            v = xl[c][t.x] * xl[c][t.y] * xl[c][t.z];
        }
        Ab[e] = f2bf(v);              // e == c*KPAD + kk
    }
}

// Single-MFMA bf16 GEMM, BK=64, double-buffered 2-phase pipeline.
// 128x128 tile, 256 threads (4 waves 2x2), wave tile 64x64, K-split, XCD swizzle.
__global__ __launch_bounds__(256, 2) void gemm2(
    const unsigned short* __restrict__ Ah, const unsigned short* __restrict__ Wh,
    float* __restrict__ ps) {
    __shared__ unsigned short S[2][2][128 * 64];   // [buf][A,W] = 64 KB

    const int tid = threadIdx.x;
    const int lane = tid & 63;
    const int w = tid >> 6;            // 0..3
    const int wr = w >> 1, wc = w & 1; // wave 64x64 sub-tile

    // XCD-aware bijective swizzle: 504 blocks = 8 XCDs x 63
    const int id = blockIdx.x;
    const int nid = (id & 7) * 63 + (id >> 3);
    const int bx = nid % 14;
    const int rest = nid / 14;
    const int by = rest % 6;
    const int bz = rest / 6;
    const int m0 = bx * 128;
    const int n0 = by * 128;
    const int kt0 = (KT64 * bz) / NSPLIT;
    const int kt1 = (KT64 * (bz + 1)) / NSPLIT;

    // ---- staging: per wave 4 cp16 each for A and W; rows [w*32, w*32+32) ----
    const int cg = (lane & 7) ^ (lane >> 3);
    const unsigned short* gA[4];
    const unsigned short* gW[4];
    #pragma unroll
    for (int q = 0; q < 4; ++q) {
        int row = w * 32 + q * 8 + (lane >> 3);
        gA[q] = Ah + (size_t)(m0 + row) * KPAD + cg * 8 + kt0 * 64;
        gW[q] = Wh + (size_t)(n0 + row) * KPAD + cg * 8 + kt0 * 64;
    }

#define STAGE(B) do { \
        _Pragma("unroll") \
        for (int q = 0; q < 4; ++q) { \
            async_cp16(gA[q], &S[B][0][(w * 256 + q * 64) * 8]); \
            async_cp16(gW[q], &S[B][1][(w * 256 + q * 64) * 8]); \
            gA[q] += 64; gW[q] += 64; \
        } \
    } while (0)

    // ---- fragment read byte-offsets (same XOR involution) ----
    const int lr = lane & 15;
    const int ck = lane >> 4;
    int offA[4][2], offW[4][2];
    #pragma unroll
    for (int mi = 0; mi < 4; ++mi) {
        int r = wr * 64 + mi * 16 + lr;
        #pragma unroll
        for (int h = 0; h < 2; ++h)
            offA[mi][h] = r * 128 + (((h * 4 + ck) ^ (r & 7)) << 4);
    }
    #pragma unroll
    for (int ni = 0; ni < 4; ++ni) {
        int r = wc * 64 + ni * 16 + lr;
        #pragma unroll
        for (int h = 0; h < 2; ++h)
            offW[ni][h] = r * 128 + (((h * 4 + ck) ^ (r & 7)) << 4);
    }

    f32x4 acc[4][4] = {};

    STAGE(0);
    __syncthreads();
    int cur = 0;
    for (int kt = kt0; kt < kt1; ++kt) {
        if (kt + 1 < kt1) STAGE(cur ^ 1);

        const char* baseA = (const char*)S[cur][0];
        const char* baseW = (const char*)S[cur][1];
        bf16x8 ah[4][2], wh[4][2];
        #pragma unroll
        for (int mi = 0; mi < 4; ++mi) {
            ah[mi][0] = *(const bf16x8*)(baseA + offA[mi][0]);
            ah[mi][1] = *(const bf16x8*)(baseA + offA[mi][1]);
        }
        #pragma unroll
        for (int ni = 0; ni < 4; ++ni) {
            wh[ni][0] = *(const bf16x8*)(baseW + offW[ni][0]);
            wh[ni][1] = *(const bf16x8*)(baseW + offW[ni][1]);
        }
        #pragma unroll
        for (int mi = 0; mi < 4; ++mi) {
            #pragma unroll
            for (int ni = 0; ni < 4; ++ni) {
                acc[mi][ni] = __builtin_amdgcn_mfma_f32_16x16x32_bf16(ah[mi][0], wh[ni][0], acc[mi][ni], 0, 0, 0);
                acc[mi][ni] = __builtin_amdgcn_mfma_f32_16x16x32_bf16(ah[mi][1], wh[ni][1], acc[mi][ni], 0, 0, 0);
            }
        }
        __syncthreads();
        cur ^= 1;
    }
#undef STAGE

    // ---- epilogue: plain stores to psum slice ----
    float* pb = ps + (size_t)bz * M_TOT * NPAD;
    #pragma unroll
    for (int mi = 0; mi < 4; ++mi) {
        #pragma unroll
        for (int ni = 0; ni < 4; ++ni) {
            const int n = n0 + wc * 64 + ni * 16 + lr;
            const int mr = m0 + wr * 64 + mi * 16 + ck * 4;
            #pragma unroll
            for (int r = 0; r < 4; ++r) {
                pb[(size_t)(mr + r) * NPAD + n] = acc[mi][ni][r];
            }
        }
    }
}

// out[b][p][c] = sum_s psum[s][b*CH+c][p] + bias[p]   (one thread per (b,p))
__global__ __launch_bounds__(256) void reduce_k(
    const float* __restrict__ ps, const float* __restrict__ bias,
    float* __restrict__ out) {
    int gid = blockIdx.x * 256 + threadIdx.x;   // exact grid: BATCH*PRED
    int b = gid / PRED, p = gid - b * PRED;
    float bv = bias[p];
    float o[CH];
    #pragma unroll
    for (int c = 0; c < CH; ++c) o[c] = bv;
    #pragma unroll
    for (int s = 0; s < NSPLIT; ++s) {
        const float* pb = ps + (size_t)s * M_TOT * NPAD + (size_t)b * CH * NPAD + p;
        #pragma unroll
        for (int c = 0; c < CH; ++c) o[c] += pb[(size_t)c * NPAD];
    }
    float* ob = out + (size_t)gid * CH;
    #pragma unroll
    for (int c = 0; c < CH; ++c) ob[c] = o[c];
}

// ================= fallback (round-1 vector kernel, proven) =================
#define BM 64
#define BN 64
#define BK 32
#define XSTRIDE 101

__global__ void build_table(ushort4* __restrict__ tab) {
    int k = blockIdx.x * blockDim.x + threadIdx.x;
    if (k < K_FEAT) tab[k] = feat_idx(k);
}

__global__ __launch_bounds__(256) void fused_poly_gemm(
    const float* __restrict__ x, const float* __restrict__ W,
    const float* __restrict__ bias, const ushort4* __restrict__ tab,
    float* __restrict__ out) {
    __shared__ float xt[BM][XSTRIDE];
    __shared__ float At[BK][BM];
    __shared__ float Wt[BK][BN];

    const int tid = threadIdx.x;
    const int m0 = blockIdx.x * BM;
    const int n0 = blockIdx.y * BN;

    for (int idx = tid; idx < BM * L; idx += 256) {
        int r = idx / L, t = idx - r * L;
        int m = m0 + r;
        int b = m / CH, c = m - b * CH;
        xt[r][t] = x[(b * L + t) * CH + c];
    }
    if (tid < BM) xt[tid][96] = 1.0f;
    __syncthreads();

    const int tm = tid & 15;
    const int tn = tid >> 4;
    float acc[4][4] = {};

    for (int k0 = 0; k0 < K_FEAT; k0 += BK) {
        #pragma unroll
        for (int q = tid; q < 512; q += 256) {
            int n = q >> 3, kq = q & 7;
            float4 wv;
            if (n0 + n < PRED) wv = *(const float4*)&W[(size_t)(n0 + n) * K_FEAT + k0 + kq * 4];
            else wv = make_float4(0.f, 0.f, 0.f, 0.f);
            Wt[kq * 4 + 0][n] = wv.x; Wt[kq * 4 + 1][n] = wv.y;
            Wt[kq * 4 + 2][n] = wv.z; Wt[kq * 4 + 3][n] = wv.w;
        }
        {
            int k = tid >> 3, mg = tid & 7;
            ushort4 e = tab[k0 + k];
            float p[8];
            #pragma unroll
            for (int mm = 0; mm < 8; ++mm) {
                int m = mg * 8 + mm;
                p[mm] = xt[m][e.x] * xt[m][e.y] * xt[m][e.z];
            }
            *(float4*)&At[k][mg * 8]     = make_float4(p[0], p[1], p[2], p[3]);
            *(float4*)&At[k][mg * 8 + 4] = make_float4(p[4], p[5], p[6], p[7]);
        }
        __syncthreads();
        #pragma unroll 8
        for (int k = 0; k < BK; ++k) {
            float4 a = *(const float4*)&At[k][tm * 4];
            float4 wv = *(const float4*)&Wt[k][tn * 4];
            acc[0][0] = fmaf(a.x, wv.x, acc[0][0]); acc[0][1] = fmaf(a.x, wv.y, acc[0][1]);
            acc[0][2] = fmaf(a.x, wv.z, acc[0][2]); acc[0][3] = fmaf(a.x, wv.w, acc[0][3]);
            acc[1][0] = fmaf(a.y, wv.x, acc[1][0]); acc[1][1] = fmaf(a.y, wv.y, acc[1][1]);
            acc[1][2] = fmaf(a.y, wv.z, acc[1][2]); acc[1][3] = fmaf(a.y, wv.w, acc[1][3]);
            acc[2][0] = fmaf(a.z, wv.x, acc[2][0]); acc[2][1] = fmaf(a.z, wv.y, acc[2][1]);
            acc[2][2] = fmaf(a.z, wv.z, acc[2][2]); acc[2][3] = fmaf(a.z, wv.w, acc[2][3]);
            acc[3][0] = fmaf(a.w, wv.x, acc[3][0]); acc[3][1] = fmaf(a.w, wv.y, acc[3][1]);
            acc[3][2] = fmaf(a.w, wv.z, acc[3][2]); acc[3][3] = fmaf(a.w, wv.w, acc[3][3]);
        }
        __syncthreads();
    }
    #pragma unroll
    for (int i = 0; i < 4; ++i) {
        int m = m0 + tm * 4 + i;
        int b = m / CH, c = m - b * CH;
        #pragma unroll
        for (int j = 0; j < 4; ++j) {
            int n = n0 + tn * 4 + j;
            if (n < PRED) out[((size_t)b * PRED + n) * CH + c] = acc[i][j] + bias[n];
        }
    }
}

extern "C" void kernel_launch(void* const* d_in, const int* in_sizes, int n_in,
                              void* d_out, int out_size, void* d_ws, size_t ws_size,
                              hipStream_t stream) {
    const float* x    = (const float*)d_in[0];
    const float* W    = (const float*)d_in[1];
    const float* bias = (const float*)d_in[2];
    float* out = (float*)d_out;
    char* ws = (char*)d_ws;

    if (ws_size >= WS_REQ) {
        unsigned short* Ah = (unsigned short*)(ws + OFF_AH);
        unsigned short* Wh = (unsigned short*)(ws + OFF_WH);
        float* psum = (float*)(ws + OFF_PS);
        ushort4* tab = (ushort4*)(ws + OFF_TAB);

        hipLaunchKernelGGL(prep1, dim3(W_BLKS + TAB_BLKS), dim3(256), 0, stream, W, Wh, tab);
        hipLaunchKernelGGL(featgen3, dim3(BATCH * 4), dim3(256), 0, stream, x, tab, Ah);
        hipLaunchKernelGGL(gemm2, dim3(14 * 6 * NSPLIT), dim3(256), 0, stream, Ah, Wh, psum);
        hipLaunchKernelGGL(reduce_k, dim3(BATCH * PRED / 256), dim3(256), 0, stream,
                           psum, bias, out);
    } else {
        ushort4* tab = (ushort4*)ws;
        hipLaunchKernelGGL(build_table, dim3((K_FEAT + 255) / 256), dim3(256), 0, stream, tab);
        dim3 grid(M_TOT / BM, (PRED + BN - 1) / BN);
        hipLaunchKernelGGL(fused_poly_gemm, grid, dim3(256), 0, stream, x, W, bias, tab, out);
    }
}